// Round 3
// baseline (1738.220 us; speedup 1.0000x reference)
//
#include <hip/hip_runtime.h>
#include <math.h>

// Problem constants
#define NTOT 32768   // T*B
#define CIN  201
#define S    67      // keypoints (seq len)
#define E    8
#define H    2
#define L    12
#define FF   16
#define OUTC 128
#define KF   536     // S*E
#define EPB  7       // elements per block
#define LPE  34      // lanes per element; lane j owns rows j and j+34
#define THREADS 256  // 7*34 = 238 active lanes

typedef float v2f __attribute__((ext_vector_type(2)));

#if __has_builtin(__builtin_amdgcn_exp2f)
#define EXP2F(x) __builtin_amdgcn_exp2f(x)
#else
#define EXP2F(x) exp2f(x)
#endif
#if __has_builtin(__builtin_amdgcn_rcpf)
#define RCPF(x) __builtin_amdgcn_rcpf(x)
#else
#define RCPF(x) (1.0f/(x))
#endif
#if __has_builtin(__builtin_amdgcn_rsqf)
#define RSQF(x) __builtin_amdgcn_rsqf(x)
#else
#define RSQF(x) rsqrtf(x)
#endif

// 0.5 (=1/sqrt(DH)) * log2(e): fold softmax scale + exp->exp2 into q
#define QSCALE 0.7213475204444817f

__device__ __forceinline__ void layernorm8v(v2f* xr, const float* __restrict__ gg,
                                            const float* __restrict__ bb) {
    v2f m = {0.f, 0.f};
    #pragma unroll
    for (int e = 0; e < E; ++e) m += xr[e];
    m *= 0.125f;
    v2f v = {0.f, 0.f};
    #pragma unroll
    for (int e = 0; e < E; ++e) { v2f d = xr[e] - m; v += d * d; }
    v *= 0.125f;
    v2f rs;
    rs.x = RSQF(v.x + 1e-5f);
    rs.y = RSQF(v.y + 1e-5f);
    #pragma unroll
    for (int e = 0; e < E; ++e) xr[e] = (xr[e] - m) * rs * gg[e] + bb[e];
}

__global__ __launch_bounds__(THREADS, 2)
void enc_kernel(const float* __restrict__ pose,
                const float* __restrict__ ew,  const float* __restrict__ ebias,
                const float* __restrict__ ipw, const float* __restrict__ ipb,
                const float* __restrict__ aow, const float* __restrict__ aob,
                const float* __restrict__ f1w, const float* __restrict__ f1b,
                const float* __restrict__ f2w, const float* __restrict__ f2b,
                const float* __restrict__ g1,  const float* __restrict__ b1,
                const float* __restrict__ g2,  const float* __restrict__ b2,
                float* __restrict__ xf)
{
    // K/V stored pre-duplicated: per (elem,head,row): float4 {x,x,y,y} and {z,z,w,w}
    // -> ds_read_b128 yields ready packed-broadcast v2f operands, zero mov overhead.
    __shared__ float4 Kd[EPB * H * S * 2];   // 30016 B
    __shared__ float4 Vd[EPB * H * S * 2];   // 30016 B

    const int lid = threadIdx.x;
    const int g   = lid / LPE;          // element in block (0..6 valid)
    const int j   = lid - g * LPE;      // first row (0..33)
    const int n   = blockIdx.x * EPB + g;
    const bool active = (g < EPB) && (n < NTOT);
    const bool r1ok = (j < LPE - 1);    // second row j+34 valid (j<33)
    const int  s1   = j + LPE;

    // ---- embed (both rows packed) ----
    v2f xr[E];
    if (active) {
        const float* p0 = pose + (size_t)n * CIN + 3 * j;
        const float* p1 = pose + (size_t)n * CIN + (r1ok ? 3 * s1 : 0);
        v2f c0 = {p0[0], p1[0]};
        v2f c1 = {p0[1], p1[1]};
        v2f c2 = {p0[2], p1[2]};
        #pragma unroll
        for (int e = 0; e < E; ++e)
            xr[e] = ebias[e] + c0 * ew[e*3+0] + c1 * ew[e*3+1] + c2 * ew[e*3+2];
    }

    #pragma unroll 1
    for (int l = 0; l < L; ++l) {
        const float* wq = ipw + l * (3*E*E);
        const float* bq = ipb + l * (3*E);
        v2f q2[E];
        if (active) {
            #pragma unroll
            for (int jj = 0; jj < E; ++jj) {        // q rows 0..7, pre-scaled
                v2f a = {bq[jj], bq[jj]};
                #pragma unroll
                for (int e = 0; e < E; ++e) a += xr[e] * wq[jj*E + e];
                q2[jj] = a * QSCALE;
            }
            v2f kv[2*E];
            #pragma unroll
            for (int jj = 0; jj < 2*E; ++jj) {      // k rows 8..15, v rows 16..23
                v2f a = {bq[E + jj], bq[E + jj]};
                #pragma unroll
                for (int e = 0; e < E; ++e) a += xr[e] * wq[(E + jj)*E + e];
                kv[jj] = a;
            }
            // store duplicated K/V for row j (.x halves)
            const int b0 = ((g*H + 0)*S + j) * 2;
            const int b1i = ((g*H + 1)*S + j) * 2;
            Kd[b0 + 0] = make_float4(kv[0].x, kv[0].x, kv[1].x, kv[1].x);
            Kd[b0 + 1] = make_float4(kv[2].x, kv[2].x, kv[3].x, kv[3].x);
            Kd[b1i+ 0] = make_float4(kv[4].x, kv[4].x, kv[5].x, kv[5].x);
            Kd[b1i+ 1] = make_float4(kv[6].x, kv[6].x, kv[7].x, kv[7].x);
            Vd[b0 + 0] = make_float4(kv[8].x, kv[8].x, kv[9].x, kv[9].x);
            Vd[b0 + 1] = make_float4(kv[10].x, kv[10].x, kv[11].x, kv[11].x);
            Vd[b1i+ 0] = make_float4(kv[12].x, kv[12].x, kv[13].x, kv[13].x);
            Vd[b1i+ 1] = make_float4(kv[14].x, kv[14].x, kv[15].x, kv[15].x);
            if (r1ok) {  // row j+34 (.y halves)
                const int c0i = ((g*H + 0)*S + s1) * 2;
                const int c1i = ((g*H + 1)*S + s1) * 2;
                Kd[c0i+ 0] = make_float4(kv[0].y, kv[0].y, kv[1].y, kv[1].y);
                Kd[c0i+ 1] = make_float4(kv[2].y, kv[2].y, kv[3].y, kv[3].y);
                Kd[c1i+ 0] = make_float4(kv[4].y, kv[4].y, kv[5].y, kv[5].y);
                Kd[c1i+ 1] = make_float4(kv[6].y, kv[6].y, kv[7].y, kv[7].y);
                Vd[c0i+ 0] = make_float4(kv[8].y, kv[8].y, kv[9].y, kv[9].y);
                Vd[c0i+ 1] = make_float4(kv[10].y, kv[10].y, kv[11].y, kv[11].y);
                Vd[c1i+ 0] = make_float4(kv[12].y, kv[12].y, kv[13].y, kv[13].y);
                Vd[c1i+ 1] = make_float4(kv[14].y, kv[14].y, kv[15].y, kv[15].y);
            }
        }
        __syncthreads();

        if (active) {
            v2f oo[E];
            #pragma unroll
            for (int h = 0; h < H; ++h) {
                const float4* K4 = &Kd[(g*H + h) * S * 2];
                const float4* V4 = &Vd[(g*H + h) * S * 2];
                const v2f qa = q2[h*4+0], qb = q2[h*4+1], qc = q2[h*4+2], qd = q2[h*4+3];
                v2f lsum = {0.f, 0.f};
                v2f o0 = {0.f,0.f}, o1 = {0.f,0.f}, o2 = {0.f,0.f}, o3 = {0.f,0.f};
                #pragma unroll
                for (int t = 0; t < S; ++t) {
                    float4 kA = K4[2*t], kB = K4[2*t+1];
                    float4 vA = V4[2*t], vB = V4[2*t+1];
                    v2f sc = qa * *(const v2f*)&kA.x + qb * *(const v2f*)&kA.z
                           + qc * *(const v2f*)&kB.x + qd * *(const v2f*)&kB.z;
                    v2f e2;
                    e2.x = EXP2F(sc.x);
                    e2.y = EXP2F(sc.y);
                    lsum += e2;
                    o0 += e2 * *(const v2f*)&vA.x;
                    o1 += e2 * *(const v2f*)&vA.z;
                    o2 += e2 * *(const v2f*)&vB.x;
                    o3 += e2 * *(const v2f*)&vB.z;
                }
                v2f inv;
                inv.x = RCPF(lsum.x);
                inv.y = RCPF(lsum.y);
                oo[h*4+0] = o0*inv; oo[h*4+1] = o1*inv;
                oo[h*4+2] = o2*inv; oo[h*4+3] = o3*inv;
            }
            // attn_out + residual + LN1
            const float* wa = aow + l*E*E;
            const float* ba = aob + l*E;
            #pragma unroll
            for (int e = 0; e < E; ++e) {
                v2f a = {ba[e], ba[e]};
                #pragma unroll
                for (int e2 = 0; e2 < E; ++e2) a += oo[e2] * wa[e*E + e2];
                xr[e] += a;
            }
            layernorm8v(xr, g1 + l*E, b1 + l*E);

            // FF
            v2f t1[FF];
            #pragma unroll
            for (int f = 0; f < FF; ++f) {
                v2f a = {f1b[l*FF + f], f1b[l*FF + f]};
                #pragma unroll
                for (int e = 0; e < E; ++e) a += xr[e] * f1w[l*FF*E + f*E + e];
                a.x = fmaxf(a.x, 0.f);
                a.y = fmaxf(a.y, 0.f);
                t1[f] = a;
            }
            #pragma unroll
            for (int e = 0; e < E; ++e) {
                v2f a = {f2b[l*E + e], f2b[l*E + e]};
                #pragma unroll
                for (int f = 0; f < FF; ++f) a += t1[f] * f2w[l*E*FF + e*FF + f];
                xr[e] += a;
            }
            layernorm8v(xr, g2 + l*E, b2 + l*E);
        }
        __syncthreads();   // protect K/V before next layer overwrites
    }

    if (active) {
        float4* o4 = (float4*)(xf + (size_t)n * KF + j * E);
        o4[0] = make_float4(xr[0].x, xr[1].x, xr[2].x, xr[3].x);
        o4[1] = make_float4(xr[4].x, xr[5].x, xr[6].x, xr[7].x);
        if (r1ok) {
            float4* o4b = (float4*)(xf + (size_t)n * KF + s1 * E);
            o4b[0] = make_float4(xr[0].y, xr[1].y, xr[2].y, xr[3].y);
            o4b[1] = make_float4(xr[4].y, xr[5].y, xr[6].y, xr[7].y);
        }
    }
}

// wt[k][c] = ow[c][k]  (268 KB, makes out_kernel W loads coalesced float4)
__global__ void tr_kernel(const float* __restrict__ ow, float* __restrict__ wt)
{
    int i = blockIdx.x * 256 + threadIdx.x;
    if (i < OUTC * KF) {
        int c = i / KF, k = i - c * KF;   // read coalesced
        wt[k * OUTC + c] = ow[i];
    }
}

// out = tanh(Xf[32768,536] @ Wt[536,128] + b)
__global__ __launch_bounds__(256, 4)
void out_kernel(const float* __restrict__ xf, const float* __restrict__ wt,
                const float* __restrict__ ob, float* __restrict__ out)
{
    __shared__ float Xs[32][68];   // 32 rows; pad 68 keeps rows 16B-aligned
    const int lid = threadIdx.x;
    const int tx  = lid & 31;      // cols tx*4 .. tx*4+3
    const int ty  = lid >> 5;      // rows ty*4 .. ty*4+3
    const int n0  = blockIdx.x * 32;

    float acc[4][4] = {};

    #pragma unroll 1
    for (int kc = 0; kc < 9; ++kc) {       // 8 chunks of 64 + 1 of 24
        const int kb = kc * 64;
        const int kw = (kc < 8) ? 64 : 24;
        __syncthreads();
        const int nvec = 32 * (kw >> 2);
        for (int i = lid; i < nvec; i += 256) {
            int r = i / (kw >> 2), kq = i - r * (kw >> 2);
            *(float4*)&Xs[r][kq*4] =
                *(const float4*)&xf[(size_t)(n0 + r) * KF + kb + kq*4];
        }
        __syncthreads();
        #pragma unroll 4
        for (int k = 0; k < kw; ++k) {
            float4 w4 = *(const float4*)&wt[(size_t)(kb + k) * OUTC + tx*4];
            #pragma unroll
            for (int i = 0; i < 4; ++i) {
                float x = Xs[ty*4 + i][k];
                acc[i][0] += x*w4.x; acc[i][1] += x*w4.y;
                acc[i][2] += x*w4.z; acc[i][3] += x*w4.w;
            }
        }
    }

    const float4 bb = *(const float4*)&ob[tx*4];
    #pragma unroll
    for (int i = 0; i < 4; ++i) {
        int r = n0 + ty*4 + i;
        float4 v;
        v.x = tanhf(acc[i][0] + bb.x);
        v.y = tanhf(acc[i][1] + bb.y);
        v.z = tanhf(acc[i][2] + bb.z);
        v.w = tanhf(acc[i][3] + bb.w);
        *(float4*)(out + (size_t)r * OUTC + tx*4) = v;
    }
}

extern "C" void kernel_launch(void* const* d_in, const int* in_sizes, int n_in,
                              void* d_out, int out_size, void* d_ws, size_t ws_size,
                              hipStream_t stream) {
    (void)in_sizes; (void)n_in; (void)out_size; (void)ws_size;
    const float* pose = (const float*)d_in[0];
    const float* ew   = (const float*)d_in[1];
    const float* eb   = (const float*)d_in[2];
    const float* ipw  = (const float*)d_in[3];
    const float* ipb  = (const float*)d_in[4];
    const float* aow  = (const float*)d_in[5];
    const float* aob  = (const float*)d_in[6];
    const float* f1w  = (const float*)d_in[7];
    const float* f1b  = (const float*)d_in[8];
    const float* f2w  = (const float*)d_in[9];
    const float* f2b  = (const float*)d_in[10];
    const float* g1   = (const float*)d_in[11];
    const float* b1   = (const float*)d_in[12];
    const float* g2   = (const float*)d_in[13];
    const float* b2   = (const float*)d_in[14];
    const float* ow   = (const float*)d_in[15];
    const float* ob   = (const float*)d_in[16];

    float* xf = (float*)d_ws;                       // 70.25 MB
    float* wt = (float*)d_ws + (size_t)NTOT * KF;   // + 268 KB

    const int grid1 = (NTOT + EPB - 1) / EPB;       // 4682
    enc_kernel<<<grid1, THREADS, 0, stream>>>(pose, ew, eb, ipw, ipb, aow, aob,
                                              f1w, f1b, f2w, f2b, g1, b1, g2, b2, xf);
    tr_kernel<<<(OUTC*KF + 255)/256, 256, 0, stream>>>(ow, wt);
    out_kernel<<<NTOT / 32, 256, 0, stream>>>(xf, wt, ob, (float*)d_out);
}

// Round 4
// 1446.991 us; speedup vs baseline: 1.2013x; 1.2013x over previous
//
#include <hip/hip_runtime.h>
#include <math.h>

// Problem constants
#define NTOT 32768   // T*B
#define CIN  201
#define S    67      // keypoints (seq len)
#define E    8
#define H    2
#define L    12
#define FF   16
#define OUTC 128
#define KF   536     // S*E
#define EPB  7       // elements per block (7*67 = 469 of 512 lanes)
#define THREADS 512
#define NPAIR 33     // t-pairs 0..65; t=66 handled scalar

typedef float v2f __attribute__((ext_vector_type(2)));

#if __has_builtin(__builtin_amdgcn_exp2f)
#define EXP2F(x) __builtin_amdgcn_exp2f(x)
#else
#define EXP2F(x) exp2f(x)
#endif
#if __has_builtin(__builtin_amdgcn_rcpf)
#define RCPF(x) __builtin_amdgcn_rcpf(x)
#else
#define RCPF(x) (1.0f/(x))
#endif
#if __has_builtin(__builtin_amdgcn_rsqf)
#define RSQF(x) __builtin_amdgcn_rsqf(x)
#else
#define RSQF(x) rsqrtf(x)
#endif

// 0.5 (=1/sqrt(DH)) * log2(e)
#define QSCALE 0.7213475204444817f

__device__ __forceinline__ void layernorm8(float* xr, const float* __restrict__ gg,
                                           const float* __restrict__ bb) {
    float m = 0.f;
    #pragma unroll
    for (int e = 0; e < E; ++e) m += xr[e];
    m *= 0.125f;
    float v = 0.f;
    #pragma unroll
    for (int e = 0; e < E; ++e) { float d = xr[e] - m; v += d * d; }
    v *= 0.125f;
    float rs = RSQF(v + 1e-5f);
    #pragma unroll
    for (int e = 0; e < E; ++e) xr[e] = (xr[e] - m) * rs * gg[e] + bb[e];
}

// Pack per-layer transposed weights into wp[L][512]:
//   [0:192)   qkvt[e][j]  = ipw[l][j][e]   (e<8, j<24)
//   [192:256) aowt[e2][e] = aow[l][e][e2]
//   [256:384) f1t[e][f]   = f1w[l][f][e]   (f<16)
//   [384:512) f2t[f][e]   = f2w[l][e][f]
__global__ void prep_kernel(const float* __restrict__ ipw, const float* __restrict__ aow,
                            const float* __restrict__ f1w, const float* __restrict__ f2w,
                            float* __restrict__ wp)
{
    int idx = blockIdx.x * 256 + threadIdx.x;
    if (idx >= L * 512) return;
    int l = idx >> 9, r = idx & 511;
    float v;
    if (r < 192)      { int e = r / 24, j = r % 24;          v = ipw[l*192 + j*8 + e]; }
    else if (r < 256) { int q = r - 192; int e2 = q / 8, e = q % 8; v = aow[l*64 + e*8 + e2]; }
    else if (r < 384) { int q = r - 256; int e = q / 16, f = q % 16; v = f1w[l*128 + f*8 + e]; }
    else              { int q = r - 384; int f = q / 8,  e = q % 8;  v = f2w[l*128 + e*16 + f]; }
    wp[idx] = v;
}

__global__ __launch_bounds__(THREADS, 4)
void enc_kernel(const float* __restrict__ pose,
                const float* __restrict__ ew,  const float* __restrict__ ebias,
                const float* __restrict__ wp,  const float* __restrict__ ipb,
                const float* __restrict__ aob,
                const float* __restrict__ f1b, const float* __restrict__ f2b,
                const float* __restrict__ g1,  const float* __restrict__ b1,
                const float* __restrict__ g2,  const float* __restrict__ b2,
                float* __restrict__ xf)
{
    // t-pair interleaved K/V: buf[0]=KA {kx_t,kx_t1,ky_t,ky_t1}, buf[1]=KB {kz,kz,kw,kw},
    // buf[2]=VA, buf[3]=VB.  4*14*34*16 = 30464 B
    __shared__ float4 buf[4][EPB * H][NPAIR + 1];

    const int lid = threadIdx.x;
    const int g   = lid / S;            // element in block (0..6 valid)
    const int s   = lid - g * S;        // keypoint row
    const int n   = blockIdx.x * EPB + g;
    const bool active = (g < EPB) && (n < NTOT);
    const int ii = s >> 1, hf = s & 1;

    // ---- embed ----
    float xr[E];
    if (active) {
        const float* p = pose + (size_t)n * CIN + 3 * s;
        float r0 = p[0], r1 = p[1], r2 = p[2];
        #pragma unroll
        for (int e = 0; e < E; ++e)
            xr[e] = ebias[e] + r0 * ew[e*3+0] + r1 * ew[e*3+1] + r2 * ew[e*3+2];
    }

    #pragma unroll 1
    for (int l = 0; l < L; ++l) {
        const float* WL   = wp + l * 512;
        const float* qkvt = WL;          // [e][24]
        const float* aowt = WL + 192;    // [e2][8]
        const float* f1t  = WL + 256;    // [e][16]
        const float* f2t  = WL + 384;    // [f][8]
        const float* bq   = ipb + l * 24;

        float qsc[E];
        if (active) {
            v2f xs[E];
            #pragma unroll
            for (int e = 0; e < E; ++e) xs[e] = (v2f){xr[e], xr[e]};

            v2f qkv[12];
            #pragma unroll
            for (int p = 0; p < 12; ++p) {
                v2f a = *(const v2f*)(bq + 2*p);
                #pragma unroll
                for (int e = 0; e < E; ++e)
                    a += xs[e] * (*(const v2f*)(qkvt + e*24 + 2*p));
                qkv[p] = a;
            }
            #pragma unroll
            for (int p = 0; p < 4; ++p) {
                qsc[2*p]   = qkv[p].x * QSCALE;
                qsc[2*p+1] = qkv[p].y * QSCALE;
            }
            // scatter K/V into t-pair interleaved layout
            #pragma unroll
            for (int h = 0; h < H; ++h) {
                const int gh = g*2 + h;
                float* pKA = (float*)&buf[0][gh][ii];
                float* pKB = (float*)&buf[1][gh][ii];
                float* pVA = (float*)&buf[2][gh][ii];
                float* pVB = (float*)&buf[3][gh][ii];
                pKA[hf] = qkv[4+2*h].x;  pKA[2+hf] = qkv[4+2*h].y;
                pKB[hf] = qkv[5+2*h].x;  pKB[2+hf] = qkv[5+2*h].y;
                pVA[hf] = qkv[8+2*h].x;  pVA[2+hf] = qkv[8+2*h].y;
                pVB[hf] = qkv[9+2*h].x;  pVB[2+hf] = qkv[9+2*h].y;
            }
        }
        __syncthreads();

        if (active) {
            float oo[E];
            #pragma unroll
            for (int h = 0; h < H; ++h) {
                const int gh = g*2 + h;
                const float4* KA = buf[0][gh];
                const float4* KB = buf[1][gh];
                const float4* VA = buf[2][gh];
                const float4* VB = buf[3][gh];
                const float q0s = qsc[4*h+0], q1s = qsc[4*h+1];
                const float q2s = qsc[4*h+2], q3s = qsc[4*h+3];
                const v2f qx2 = {q0s, q0s}, qy2 = {q1s, q1s};
                const v2f qz2 = {q2s, q2s}, qw2 = {q3s, q3s};
                v2f l2 = {0.f, 0.f};
                v2f ox = {0.f,0.f}, oy = {0.f,0.f}, oz = {0.f,0.f}, ow = {0.f,0.f};
                #pragma unroll
                for (int i = 0; i < NPAIR; ++i) {       // t = 0..65
                    float4 ka = KA[i], kb = KB[i];
                    float4 va = VA[i], vb = VB[i];
                    v2f sc = qx2 * *(const v2f*)&ka.x + qy2 * *(const v2f*)&ka.z
                           + qz2 * *(const v2f*)&kb.x + qw2 * *(const v2f*)&kb.z;
                    v2f e2;
                    e2.x = EXP2F(sc.x);
                    e2.y = EXP2F(sc.y);
                    l2 += e2;
                    ox += e2 * *(const v2f*)&va.x;
                    oy += e2 * *(const v2f*)&va.z;
                    oz += e2 * *(const v2f*)&vb.x;
                    ow += e2 * *(const v2f*)&vb.z;
                }
                // t = 66 singleton: halves .x/.z of slot 33
                float4 ka = KA[NPAIR], kb = KB[NPAIR];
                float4 va = VA[NPAIR], vb = VB[NPAIR];
                float sc1 = q0s*ka.x + q1s*ka.z + q2s*kb.x + q3s*kb.z;
                float e1  = EXP2F(sc1);
                float lsum = l2.x + l2.y + e1;
                float inv  = RCPF(lsum);
                oo[4*h+0] = (ox.x + ox.y + e1*va.x) * inv;
                oo[4*h+1] = (oy.x + oy.y + e1*va.z) * inv;
                oo[4*h+2] = (oz.x + oz.y + e1*vb.x) * inv;
                oo[4*h+3] = (ow.x + ow.y + e1*vb.z) * inv;
            }

            // attn_out + residual + LN1 (packed over output-pairs)
            {
                const float* ba = aob + l*E;
                v2f os[E];
                #pragma unroll
                for (int e2 = 0; e2 < E; ++e2) os[e2] = (v2f){oo[e2], oo[e2]};
                #pragma unroll
                for (int p = 0; p < 4; ++p) {
                    v2f a = *(const v2f*)(ba + 2*p);
                    #pragma unroll
                    for (int e2 = 0; e2 < E; ++e2)
                        a += os[e2] * (*(const v2f*)(aowt + e2*8 + 2*p));
                    xr[2*p]   += a.x;
                    xr[2*p+1] += a.y;
                }
            }
            layernorm8(xr, g1 + l*E, b1 + l*E);

            // FF (packed)
            {
                const float* fb1 = f1b + l*FF;
                const float* fb2 = f2b + l*E;
                v2f xs[E];
                #pragma unroll
                for (int e = 0; e < E; ++e) xs[e] = (v2f){xr[e], xr[e]};
                v2f t1p[8];
                #pragma unroll
                for (int p = 0; p < 8; ++p) {
                    v2f a = *(const v2f*)(fb1 + 2*p);
                    #pragma unroll
                    for (int e = 0; e < E; ++e)
                        a += xs[e] * (*(const v2f*)(f1t + e*16 + 2*p));
                    a.x = fmaxf(a.x, 0.f);
                    a.y = fmaxf(a.y, 0.f);
                    t1p[p] = a;
                }
                v2f ts[FF];
                #pragma unroll
                for (int p = 0; p < 8; ++p) {
                    ts[2*p]   = (v2f){t1p[p].x, t1p[p].x};
                    ts[2*p+1] = (v2f){t1p[p].y, t1p[p].y};
                }
                #pragma unroll
                for (int p = 0; p < 4; ++p) {
                    v2f a = *(const v2f*)(fb2 + 2*p);
                    #pragma unroll
                    for (int f = 0; f < FF; ++f)
                        a += ts[f] * (*(const v2f*)(f2t + f*8 + 2*p));
                    xr[2*p]   += a.x;
                    xr[2*p+1] += a.y;
                }
            }
            layernorm8(xr, g2 + l*E, b2 + l*E);
        }
        __syncthreads();   // protect K/V before next layer overwrites
    }

    if (active) {
        float4* o4 = (float4*)(xf + (size_t)n * KF + s * E);
        o4[0] = make_float4(xr[0], xr[1], xr[2], xr[3]);
        o4[1] = make_float4(xr[4], xr[5], xr[6], xr[7]);
    }
}

// wt[k][c] = ow[c][k]
__global__ void tr_kernel(const float* __restrict__ ow, float* __restrict__ wt)
{
    int i = blockIdx.x * 256 + threadIdx.x;
    if (i < OUTC * KF) {
        int c = i / KF, k = i - c * KF;
        wt[k * OUTC + c] = ow[i];
    }
}

// out = tanh(Xf[32768,536] @ Wt[536,128] + b)
__global__ __launch_bounds__(256, 4)
void out_kernel(const float* __restrict__ xf, const float* __restrict__ wt,
                const float* __restrict__ ob, float* __restrict__ out)
{
    __shared__ float Xs[32][68];
    const int lid = threadIdx.x;
    const int tx  = lid & 31;
    const int ty  = lid >> 5;
    const int n0  = blockIdx.x * 32;

    float acc[4][4] = {};

    #pragma unroll 1
    for (int kc = 0; kc < 9; ++kc) {
        const int kb = kc * 64;
        const int kw = (kc < 8) ? 64 : 24;
        __syncthreads();
        const int nvec = 32 * (kw >> 2);
        for (int i = lid; i < nvec; i += 256) {
            int r = i / (kw >> 2), kq = i - r * (kw >> 2);
            *(float4*)&Xs[r][kq*4] =
                *(const float4*)&xf[(size_t)(n0 + r) * KF + kb + kq*4];
        }
        __syncthreads();
        #pragma unroll 4
        for (int k = 0; k < kw; ++k) {
            float4 w4 = *(const float4*)&wt[(size_t)(kb + k) * OUTC + tx*4];
            #pragma unroll
            for (int i = 0; i < 4; ++i) {
                float x = Xs[ty*4 + i][k];
                acc[i][0] += x*w4.x; acc[i][1] += x*w4.y;
                acc[i][2] += x*w4.z; acc[i][3] += x*w4.w;
            }
        }
    }

    const float4 bb = *(const float4*)&ob[tx*4];
    #pragma unroll
    for (int i = 0; i < 4; ++i) {
        int r = n0 + ty*4 + i;
        float4 v;
        v.x = tanhf(acc[i][0] + bb.x);
        v.y = tanhf(acc[i][1] + bb.y);
        v.z = tanhf(acc[i][2] + bb.z);
        v.w = tanhf(acc[i][3] + bb.w);
        *(float4*)(out + (size_t)r * OUTC + tx*4) = v;
    }
}

extern "C" void kernel_launch(void* const* d_in, const int* in_sizes, int n_in,
                              void* d_out, int out_size, void* d_ws, size_t ws_size,
                              hipStream_t stream) {
    (void)in_sizes; (void)n_in; (void)out_size; (void)ws_size;
    const float* pose = (const float*)d_in[0];
    const float* ew   = (const float*)d_in[1];
    const float* eb   = (const float*)d_in[2];
    const float* ipw  = (const float*)d_in[3];
    const float* ipb  = (const float*)d_in[4];
    const float* aow  = (const float*)d_in[5];
    const float* aob  = (const float*)d_in[6];
    const float* f1w  = (const float*)d_in[7];
    const float* f1b  = (const float*)d_in[8];
    const float* f2w  = (const float*)d_in[9];
    const float* f2b  = (const float*)d_in[10];
    const float* g1   = (const float*)d_in[11];
    const float* b1   = (const float*)d_in[12];
    const float* g2   = (const float*)d_in[13];
    const float* b2   = (const float*)d_in[14];
    const float* ow   = (const float*)d_in[15];
    const float* ob   = (const float*)d_in[16];

    float* xf = (float*)d_ws;                               // 70.25 MB
    float* wt = xf + (size_t)NTOT * KF;                     // 268 KB
    float* wp = wt + (size_t)KF * OUTC;                     // 24 KB

    prep_kernel<<<(L*512 + 255)/256, 256, 0, stream>>>(ipw, aow, f1w, f2w, wp);
    const int grid1 = (NTOT + EPB - 1) / EPB;               // 4682
    enc_kernel<<<grid1, THREADS, 0, stream>>>(pose, ew, eb, wp, ipb, aob,
                                              f1b, f2b, g1, b1, g2, b2, xf);
    tr_kernel<<<(OUTC*KF + 255)/256, 256, 0, stream>>>(ow, wt);
    out_kernel<<<NTOT / 32, 256, 0, stream>>>(xf, wt, ob, (float*)d_out);
}